// Round 1
// baseline (1126.203 us; speedup 1.0000x reference)
//
#include <hip/hip_runtime.h>
#include <hip/hip_bf16.h>

typedef _Float16 hh4 __attribute__((ext_vector_type(4)));
typedef _Float16 hh8 __attribute__((ext_vector_type(8)));
typedef float fx4 __attribute__((ext_vector_type(4)));

#define D_DIM 256
#define N_DIM 512
#define BM 64
#define STRIDE_Q 264   // 256 + 8 halves pad
#define STRIDE_P 520   // 512 + 8 halves pad

// ---------------------------------------------------------------------------
// Prep: normalize emb rows -> bankn (fp16, [N][D]); raw emb transposed ->
// embT (fp16, [D][N]). 8 blocks x 256 threads, 4 lanes per row.
// ---------------------------------------------------------------------------
__global__ void prep_kernel(const float* __restrict__ emb,
                            _Float16* __restrict__ bankn,
                            _Float16* __restrict__ embT) {
  const int tid = threadIdx.x;
  const int rl = tid >> 2;          // 0..63 row within block
  const int sub = tid & 3;          // 4 lanes per row
  const int row = blockIdx.x * 64 + rl;   // 0..511

  const float4* src = reinterpret_cast<const float4*>(emb + (size_t)row * D_DIM);
  float4 v[16];
  float ss = 0.f;
#pragma unroll
  for (int i = 0; i < 16; ++i) {
    v[i] = src[i * 4 + sub];        // element k = i*16 + sub*4
    ss += v[i].x * v[i].x + v[i].y * v[i].y + v[i].z * v[i].z + v[i].w * v[i].w;
  }
  ss += __shfl_xor(ss, 1);
  ss += __shfl_xor(ss, 2);
  const float inv = rsqrtf(fmaxf(ss, 1e-24f));

#pragma unroll
  for (int i = 0; i < 16; ++i) {
    const int k = i * 16 + sub * 4;
    hh4 h;
    h.x = (_Float16)(v[i].x * inv);
    h.y = (_Float16)(v[i].y * inv);
    h.z = (_Float16)(v[i].z * inv);
    h.w = (_Float16)(v[i].w * inv);
    *reinterpret_cast<hh4*>(&bankn[(size_t)row * D_DIM + k]) = h;
    // raw (un-normalized) emb, transposed for GEMM2 B-fragments
    embT[(size_t)(k + 0) * N_DIM + row] = (_Float16)v[i].x;
    embT[(size_t)(k + 1) * N_DIM + row] = (_Float16)v[i].y;
    embT[(size_t)(k + 2) * N_DIM + row] = (_Float16)v[i].z;
    embT[(size_t)(k + 3) * N_DIM + row] = (_Float16)v[i].w;
  }
}

// ---------------------------------------------------------------------------
// Fused: normalize query tile -> GEMM1 (qn @ bankn^T) -> softmax -> write p
// -> GEMM2 (p @ emb) -> write vec.  64 queries per workgroup, 4 waves.
// ---------------------------------------------------------------------------
__global__ __launch_bounds__(256, 2) void fused_kernel(
    const float* __restrict__ query,
    const _Float16* __restrict__ bankn,
    const _Float16* __restrict__ embT,
    float* __restrict__ out_vec,
    float* __restrict__ out_p) {
  __shared__ __align__(16) _Float16 smem[BM * STRIDE_P];  // qn (stride 264) then p (stride 520)
  __shared__ float scratch[2 * BM * 4];                   // [0..255] row-max partials, [256..511] row-sum partials

  const int tid = threadIdx.x;
  const size_t b0 = (size_t)blockIdx.x * BM;

  // ---- Phase 0: load + l2-normalize 64 query rows -> smem fp16 ----
  {
    const int rl = tid >> 2, sub = tid & 3;
    const float4* src = reinterpret_cast<const float4*>(query + (b0 + rl) * D_DIM);
    float4 v[16];
    float ss = 0.f;
#pragma unroll
    for (int i = 0; i < 16; ++i) {
      v[i] = src[i * 4 + sub];
      ss += v[i].x * v[i].x + v[i].y * v[i].y + v[i].z * v[i].z + v[i].w * v[i].w;
    }
    ss += __shfl_xor(ss, 1);
    ss += __shfl_xor(ss, 2);
    const float inv = rsqrtf(fmaxf(ss, 1e-24f));
#pragma unroll
    for (int i = 0; i < 16; ++i) {
      const int k = i * 16 + sub * 4;
      hh4 h;
      h.x = (_Float16)(v[i].x * inv);
      h.y = (_Float16)(v[i].y * inv);
      h.z = (_Float16)(v[i].z * inv);
      h.w = (_Float16)(v[i].w * inv);
      *reinterpret_cast<hh4*>(&smem[rl * STRIDE_Q + k]) = h;
    }
  }
  __syncthreads();

  const int wave = tid >> 6;
  const int lane = tid & 63;
  const int q4 = lane >> 4;   // quad: A/B k-group, C row-group
  const int ln = lane & 15;   // A row / B col / C col

  // ---- Phase 1: GEMM1  sim[64][128w..128w+128) per wave, K=256 ----
  fx4 acc[4][8];
#pragma unroll
  for (int mt = 0; mt < 4; ++mt)
#pragma unroll
    for (int nt = 0; nt < 8; ++nt) acc[mt][nt] = 0;

#pragma unroll 2
  for (int kk = 0; kk < 8; ++kk) {
    hh8 a[4], b[8];
#pragma unroll
    for (int mt = 0; mt < 4; ++mt)
      a[mt] = *reinterpret_cast<const hh8*>(&smem[(mt * 16 + ln) * STRIDE_Q + kk * 32 + q4 * 8]);
#pragma unroll
    for (int nt = 0; nt < 8; ++nt)
      b[nt] = *reinterpret_cast<const hh8*>(
          &bankn[(size_t)(128 * wave + nt * 16 + ln) * D_DIM + kk * 32 + q4 * 8]);
#pragma unroll
    for (int nt = 0; nt < 8; ++nt)
#pragma unroll
      for (int mt = 0; mt < 4; ++mt)
        acc[mt][nt] = __builtin_amdgcn_mfma_f32_16x16x32_f16(a[mt], b[nt], acc[mt][nt], 0, 0, 0);
  }

  // ---- Phase 2: softmax over full row (cross-wave via LDS scratch) ----
  // lane holds rows m = mt*16 + q4*4 + r, cols 128*wave + nt*16 + ln
  float pm[4][4];
#pragma unroll
  for (int mt = 0; mt < 4; ++mt)
#pragma unroll
    for (int r = 0; r < 4; ++r) {
      float m = acc[mt][0][r];
#pragma unroll
      for (int nt = 1; nt < 8; ++nt) m = fmaxf(m, acc[mt][nt][r]);
      m = fmaxf(m, __shfl_xor(m, 1));
      m = fmaxf(m, __shfl_xor(m, 2));
      m = fmaxf(m, __shfl_xor(m, 4));
      m = fmaxf(m, __shfl_xor(m, 8));
      pm[mt][r] = m;
    }
  if (ln == 0) {
#pragma unroll
    for (int mt = 0; mt < 4; ++mt)
#pragma unroll
      for (int r = 0; r < 4; ++r)
        scratch[(mt * 16 + q4 * 4 + r) * 4 + wave] = pm[mt][r];
  }
  __syncthreads();

  float ps[4][4];
#pragma unroll
  for (int mt = 0; mt < 4; ++mt)
#pragma unroll
    for (int r = 0; r < 4; ++r) {
      const int mi = mt * 16 + q4 * 4 + r;
      const float gm = fmaxf(fmaxf(scratch[mi * 4 + 0], scratch[mi * 4 + 1]),
                             fmaxf(scratch[mi * 4 + 2], scratch[mi * 4 + 3]));
      float s = 0.f;
#pragma unroll
      for (int nt = 0; nt < 8; ++nt) {
        const float e = __expf(acc[mt][nt][r] - gm);
        acc[mt][nt][r] = e;
        s += e;
      }
      s += __shfl_xor(s, 1);
      s += __shfl_xor(s, 2);
      s += __shfl_xor(s, 4);
      s += __shfl_xor(s, 8);
      ps[mt][r] = s;
    }
  if (ln == 0) {
#pragma unroll
    for (int mt = 0; mt < 4; ++mt)
#pragma unroll
      for (int r = 0; r < 4; ++r)
        scratch[256 + (mt * 16 + q4 * 4 + r) * 4 + wave] = ps[mt][r];
  }
  __syncthreads();

  // ---- finalize p: write fp32 to global, fp16 to smem (overwrites qn) ----
#pragma unroll
  for (int mt = 0; mt < 4; ++mt)
#pragma unroll
    for (int r = 0; r < 4; ++r) {
      const int mi = mt * 16 + q4 * 4 + r;
      const float S = scratch[256 + mi * 4 + 0] + scratch[256 + mi * 4 + 1] +
                      scratch[256 + mi * 4 + 2] + scratch[256 + mi * 4 + 3];
      const float invS = 1.0f / S;
      const size_t prow = (b0 + mi) * N_DIM + 128 * wave + ln;
#pragma unroll
      for (int nt = 0; nt < 8; ++nt) {
        const float p = acc[mt][nt][r] * invS;
        out_p[prow + nt * 16] = p;
        smem[mi * STRIDE_P + 128 * wave + nt * 16 + ln] = (_Float16)p;
      }
    }
  __syncthreads();

  // ---- Phase 3: GEMM2  vec[64][64w..64w+64) per wave, K=512 ----
  fx4 acc2[4][4];
#pragma unroll
  for (int mt = 0; mt < 4; ++mt)
#pragma unroll
    for (int dt = 0; dt < 4; ++dt) acc2[mt][dt] = 0;

#pragma unroll 2
  for (int kk = 0; kk < 16; ++kk) {
    hh8 a[4], b[4];
#pragma unroll
    for (int mt = 0; mt < 4; ++mt)
      a[mt] = *reinterpret_cast<const hh8*>(&smem[(mt * 16 + ln) * STRIDE_P + kk * 32 + q4 * 8]);
#pragma unroll
    for (int dt = 0; dt < 4; ++dt)
      b[dt] = *reinterpret_cast<const hh8*>(
          &embT[(size_t)(64 * wave + dt * 16 + ln) * N_DIM + kk * 32 + q4 * 8]);
#pragma unroll
    for (int dt = 0; dt < 4; ++dt)
#pragma unroll
      for (int mt = 0; mt < 4; ++mt)
        acc2[mt][dt] = __builtin_amdgcn_mfma_f32_16x16x32_f16(a[mt], b[dt], acc2[mt][dt], 0, 0, 0);
  }

#pragma unroll
  for (int mt = 0; mt < 4; ++mt)
#pragma unroll
    for (int r = 0; r < 4; ++r) {
      const size_t vrow = (b0 + mt * 16 + q4 * 4 + r) * D_DIM + 64 * wave + ln;
#pragma unroll
      for (int dt = 0; dt < 4; ++dt)
        out_vec[vrow + dt * 16] = acc2[mt][dt][r];
    }
}

extern "C" void kernel_launch(void* const* d_in, const int* in_sizes, int n_in,
                              void* d_out, int out_size, void* d_ws, size_t ws_size,
                              hipStream_t stream) {
  const float* query = (const float*)d_in[0];
  const float* emb = (const float*)d_in[1];
  const int B = in_sizes[0] / D_DIM;  // 262144

  float* out_vec = (float*)d_out;                      // (B, 256) first
  float* out_p = out_vec + (size_t)B * D_DIM;          // then (B, 512)

  _Float16* bankn = (_Float16*)d_ws;                   // [N][D] fp16, normalized
  _Float16* embT = bankn + (size_t)N_DIM * D_DIM;      // [D][N] fp16, raw transposed

  prep_kernel<<<8, 256, 0, stream>>>(emb, bankn, embT);
  fused_kernel<<<B / BM, 256, 0, stream>>>(query, bankn, embT, out_vec, out_p);
}